// Round 2
// baseline (7805.527 us; speedup 1.0000x reference)
//
#include <hip/hip_runtime.h>

// MultiSemanticSPR: B=4096, H=1024, S=7
// Round 1: chunked fp32 baseline. Batch processed in 4 chunks of 1024 rows so
// peak workspace = 3 chunk slabs (X/Y/Z) = 88.2 MB (round-0's 352 MB likely
// overflowed d_ws -> GPU fault). GEMM: 128x128 (or 64x128) tile, 8x8 (4x8)
// microtile, BK=16, LDS-staged fp32. ~437 GFLOP total.

#define H 1024
#define SGS 7
#define BATCH 4096
#define BC 1024   // batch chunk rows

typedef long long i64;

__device__ __forceinline__ float block_red(float v, float* scr) {
#pragma unroll
  for (int o = 32; o; o >>= 1) v += __shfl_down(v, o);
  int w = threadIdx.x >> 6;
  if ((threadIdx.x & 63) == 0) scr[w] = v;
  __syncthreads();
  v = scr[0] + scr[1] + scr[2] + scr[3];
  __syncthreads();
  return v;
}

__device__ __forceinline__ void block_red2(float& a, float& b, float* scr) {
#pragma unroll
  for (int o = 32; o; o >>= 1) { a += __shfl_down(a, o); b += __shfl_down(b, o); }
  int w = threadIdx.x >> 6;
  if ((threadIdx.x & 63) == 0) { scr[w] = a; scr[4 + w] = b; }
  __syncthreads();
  a = scr[0] + scr[1] + scr[2] + scr[3];
  b = scr[4] + scr[5] + scr[6] + scr[7];
  __syncthreads();
}

// ------------- fp32 GEMM: C = A@B (+bias) (+relu), tile BM x 128, BK=16 ----
// M multiple of BM, N multiple of 128, K multiple of 16. Grid (N/128, M/BM, z).
template <int BM>
__global__ __launch_bounds__(256) void sgemm_t(
    const float* __restrict__ A, int lda, i64 sA,
    const float* __restrict__ Bm, int ldb, i64 sB,
    float* __restrict__ C, int ldc, i64 sC,
    const float* __restrict__ bias, i64 sBias,
    int K, int relu)
{
  constexpr int RM = BM / 16;  // rows per thread: 8 (BM=128) or 4 (BM=64)
  A  += (i64)blockIdx.z * sA;
  Bm += (i64)blockIdx.z * sB;
  C  += (i64)blockIdx.z * sC;
  const float* bi = bias ? bias + (i64)blockIdx.z * sBias : nullptr;

  __shared__ float As[16][BM + 4];
  __shared__ float Bs[16][128 + 4];

  const int tid = threadIdx.x;
  const int tx = tid & 15, ty = tid >> 4;
  const i64 row0 = (i64)blockIdx.y * BM;
  const i64 col0 = (i64)blockIdx.x * 128;

  const int ar = tid >> 2, akc = (tid & 3) * 4;   // A tile: 64(x2) rows x 16 k
  const int bkr = tid >> 5, bnc = (tid & 31) * 4; // B tile: 8(x2) k x 128 cols

  const float* Aptr = A + (row0 + ar) * (i64)lda + akc;
  const float* Bptr = Bm + (i64)bkr * ldb + col0 + bnc;

  float acc[RM][8];
#pragma unroll
  for (int i = 0; i < RM; ++i)
#pragma unroll
    for (int j = 0; j < 8; ++j) acc[i][j] = 0.f;

  for (int k0 = 0; k0 < K; k0 += 16) {
    float4 a0 = *(const float4*)(Aptr + k0);
    float4 a1;
    if constexpr (BM == 128) a1 = *(const float4*)(Aptr + (i64)64 * lda + k0);
    float4 b0 = *(const float4*)(Bptr + (i64)k0 * ldb);
    float4 b1 = *(const float4*)(Bptr + (i64)(k0 + 8) * ldb);
    __syncthreads();  // prior inner-loop reads done before overwrite
    As[akc + 0][ar] = a0.x; As[akc + 1][ar] = a0.y;
    As[akc + 2][ar] = a0.z; As[akc + 3][ar] = a0.w;
    if constexpr (BM == 128) {
      As[akc + 0][ar + 64] = a1.x; As[akc + 1][ar + 64] = a1.y;
      As[akc + 2][ar + 64] = a1.z; As[akc + 3][ar + 64] = a1.w;
    }
    *(float4*)&Bs[bkr][bnc] = b0;
    *(float4*)&Bs[bkr + 8][bnc] = b1;
    __syncthreads();
#pragma unroll
    for (int k = 0; k < 16; ++k) {
      float av[RM];
      if constexpr (BM == 128) {
        float4 x = *(const float4*)&As[k][ty * 8];
        float4 y = *(const float4*)&As[k][ty * 8 + 4];
        av[0] = x.x; av[1] = x.y; av[2] = x.z; av[3] = x.w;
        av[4] = y.x; av[5] = y.y; av[6] = y.z; av[7] = y.w;
      } else {
        float4 x = *(const float4*)&As[k][ty * 4];
        av[0] = x.x; av[1] = x.y; av[2] = x.z; av[3] = x.w;
      }
      float4 bA = *(const float4*)&Bs[k][tx * 8];
      float4 bB = *(const float4*)&Bs[k][tx * 8 + 4];
      float bv[8] = {bA.x, bA.y, bA.z, bA.w, bB.x, bB.y, bB.z, bB.w};
#pragma unroll
      for (int i = 0; i < RM; ++i)
#pragma unroll
        for (int j = 0; j < 8; ++j) acc[i][j] += av[i] * bv[j];
    }
  }

  float bvv[8];
#pragma unroll
  for (int j = 0; j < 8; ++j) bvv[j] = bi ? bi[col0 + tx * 8 + j] : 0.f;
  const i64 crow = row0 + (i64)ty * RM, ccol = col0 + tx * 8;
#pragma unroll
  for (int i = 0; i < RM; ++i) {
    float o[8];
#pragma unroll
    for (int j = 0; j < 8; ++j) {
      float v = acc[i][j] + bvv[j];
      o[j] = relu ? fmaxf(v, 0.f) : v;
    }
    *(float4*)&C[(crow + i) * (i64)ldc + ccol]     = make_float4(o[0], o[1], o[2], o[3]);
    *(float4*)&C[(crow + i) * (i64)ldc + ccol + 4] = make_float4(o[4], o[5], o[6], o[7]);
  }
}

// ---------------- LayerNorm + exact GELU, one row (H=1024) per block --------
__global__ __launch_bounds__(256) void ln_gelu_k(
    const float* __restrict__ x, const float* __restrict__ gamma,
    const float* __restrict__ beta, float* __restrict__ y)
{
  __shared__ float scr[8];
  const i64 row = blockIdx.x;
  const float* xr = x + row * H;
  float* yr = y + row * H;
  const int c = threadIdx.x * 4;
  float4 v = *(const float4*)(xr + c);
  float s = v.x + v.y + v.z + v.w;
  float q = v.x * v.x + v.y * v.y + v.z * v.z + v.w * v.w;
  block_red2(s, q, scr);
  const float mu = s * (1.f / H);
  const float var = q * (1.f / H) - mu * mu;
  const float rstd = rsqrtf(var + 1e-5f);
  float4 g4 = *(const float4*)(gamma + c);
  float4 b4 = *(const float4*)(beta + c);
  float t[4] = {(v.x - mu) * rstd * g4.x + b4.x,
                (v.y - mu) * rstd * g4.y + b4.y,
                (v.z - mu) * rstd * g4.z + b4.z,
                (v.w - mu) * rstd * g4.w + b4.w};
  float o[4];
#pragma unroll
  for (int i = 0; i < 4; ++i)
    o[i] = 0.5f * t[i] * (1.f + erff(t[i] * 0.70710678118654752f));
  *(float4*)(yr + c) = make_float4(o[0], o[1], o[2], o[3]);
}

// ------------- Modified Gram-Schmidt, in-place safe (block-exclusive) ------
__global__ __launch_bounds__(256) void gram_schmidt_k(
    const float* __restrict__ sem, float* __restrict__ h)
{
  __shared__ float V[SGS][H];
  __shared__ float scr[8];
  const i64 b = blockIdx.x;
  const float* src = sem + b * (i64)(SGS * H);
  float* dst = h + b * (i64)(SGS * H);
  for (int e = threadIdx.x; e < SGS * H; e += 256) ((float*)V)[e] = src[e];
  __syncthreads();
  for (int i = 0; i < SGS; ++i) {
    for (int j = 0; j < i; ++j) {
      float dd = 0.f, cc = 0.f;
      for (int e = threadIdx.x; e < H; e += 256) {
        float qv = V[j][e], xv = V[i][e];
        dd += qv * qv; cc += xv * qv;
      }
      block_red2(dd, cc, scr);
      const float proj = (sqrtf(dd) > 1e-6f) ? cc / dd : 0.f;
      for (int e = threadIdx.x; e < H; e += 256) V[i][e] -= proj * V[j][e];
      __syncthreads();
    }
    float nn = 0.f;
    for (int e = threadIdx.x; e < H; e += 256) { float xv = V[i][e]; nn += xv * xv; }
    nn = block_red(nn, scr);
    const float n = sqrtf(nn);
    if (n > 1e-6f) {  // fallback branch statistically unreachable here
      const float inv = 1.f / n;
      for (int e = threadIdx.x; e < H; e += 256) V[i][e] *= inv;
    }
    __syncthreads();
  }
  for (int e = threadIdx.x; e < SGS * H; e += 256) dst[e] = ((float*)V)[e];
}

// --------- loss: sum((p-h)^2) per (b,s) into part[s*BATCH + b_global] ------
__global__ __launch_bounds__(256) void loss_part_k(
    const float* __restrict__ p, const float* __restrict__ h,
    float* __restrict__ part)  // part pre-offset by chunk row0
{
  __shared__ float scr[8];
  const i64 b = blockIdx.x;
  const int s = blockIdx.y;
  const i64 base = b * (i64)(SGS * H) + (i64)s * H;
  const int e = threadIdx.x * 4;
  float4 pv = *(const float4*)(p + base + e);
  float4 hv = *(const float4*)(h + base + e);
  float d0 = pv.x - hv.x, d1 = pv.y - hv.y, d2 = pv.z - hv.z, d3 = pv.w - hv.w;
  float acc = d0 * d0 + d1 * d1 + d2 * d2 + d3 * d3;
  acc = block_red(acc, scr);
  if (threadIdx.x == 0) part[(i64)s * BATCH + b] = acc;
}

__global__ __launch_bounds__(256) void loss_red_k(
    const float* __restrict__ part, float* __restrict__ losses)
{
  __shared__ float scr[8];
  const int s = blockIdx.x;
  float acc = 0.f;
  for (int e = threadIdx.x; e < BATCH; e += 256) acc += part[(i64)s * BATCH + e];
  acc = block_red(acc, scr);
  if (threadIdx.x == 0) losses[s] = acc / (float)((i64)BATCH * H);
}

__global__ void finalize_k(const float* __restrict__ losses,
                           const float* __restrict__ w, float* __restrict__ o)
{
  if (threadIdx.x == 0) {
    float t = 0.f;
#pragma unroll
    for (int s = 0; s < SGS; ++s) { float l = losses[s]; o[1 + s] = l; t += w[s] * l; }
    o[0] = t;
  }
}

// ---------------------------------------------------------------------------
extern "C" void kernel_launch(void* const* d_in, const int* in_sizes, int n_in,
                              void* d_out, int out_size, void* d_ws, size_t ws_size,
                              hipStream_t stream)
{
  (void)in_sizes; (void)n_in; (void)out_size; (void)ws_size;
  const float* sent    = (const float*)d_in[0];
  const float* decompW = (const float*)d_in[1];
  const float* ln_g    = (const float*)d_in[2];
  const float* ln_b    = (const float*)d_in[3];
  const float* pw1     = (const float*)d_in[4];
  const float* pb1     = (const float*)d_in[5];
  const float* pw2     = (const float*)d_in[6];
  const float* pb2     = (const float*)d_in[7];
  const float* qw1     = (const float*)d_in[8];
  const float* qb1     = (const float*)d_in[9];
  const float* qw2     = (const float*)d_in[10];
  const float* qb2     = (const float*)d_in[11];
  const float* fw1     = (const float*)d_in[12];
  const float* fb1     = (const float*)d_in[13];
  const float* fw2     = (const float*)d_in[14];
  const float* fb2     = (const float*)d_in[15];
  const float* semw    = (const float*)d_in[16];
  float* out = (float*)d_out;

  // workspace: 3 chunk slabs + loss partials   (~88.2 MB total)
  float* ws = (float*)d_ws;
  const i64 CS = (i64)BC * SGS * H;             // 7,340,032 floats / chunk slab
  float* X     = ws;                            // sem -> h (MGS in place)
  float* Y     = ws + CS;                       // z1 -> p1 -> fusion hidden t
  float* Z     = ws + 2 * CS;                   // z2 -> p
  float* part  = ws + 3 * CS;                   // SGS*BATCH loss partials
  float* losses= part + (i64)SGS * BATCH;       // SGS floats

  const dim3 blk(256);
  const i64 HH = (i64)H * H;

  for (int c = 0; c < BATCH / BC; ++c) {
    const i64 r0 = (i64)c * BC;
    // 1) decomposed = sent[chunk] @ decompW     (BC x 7168, K=1024)
    sgemm_t<128><<<dim3(56, BC / 128, 1), blk, 0, stream>>>(
        sent + r0 * H, H, 0, decompW, SGS * H, 0, X, SGS * H, 0, nullptr, 0, H, 0);
    // 2) sem = gelu(LN(decomposed)) in place
    ln_gelu_k<<<dim3(BC * SGS), blk, 0, stream>>>(X, ln_g, ln_b, X);
    // 3) h = MGS(sem), in place
    gram_schmidt_k<<<dim3(BC), blk, 0, stream>>>(X, X);
    // 4) z1 = relu(h @ pw1 + pb1)
    sgemm_t<128><<<dim3(8, BC / 128, SGS), blk, 0, stream>>>(
        X, SGS * H, H, pw1, H, HH, Y, SGS * H, H, pb1, H, H, 1);
    // 5) z2 = z1 @ pw2 + pb2
    sgemm_t<128><<<dim3(8, BC / 128, SGS), blk, 0, stream>>>(
        Y, SGS * H, H, pw2, H, HH, Z, SGS * H, H, pb2, H, H, 0);
    // 6) p1 = relu(z2 @ qw1 + qb1)
    sgemm_t<128><<<dim3(8, BC / 128, SGS), blk, 0, stream>>>(
        Z, SGS * H, H, qw1, H, HH, Y, SGS * H, H, qb1, H, H, 1);
    // 7) p = p1 @ qw2 + qb2
    sgemm_t<128><<<dim3(8, BC / 128, SGS), blk, 0, stream>>>(
        Y, SGS * H, H, qw2, H, HH, Z, SGS * H, H, qb2, H, H, 0);
    // 8) loss partials for this chunk
    loss_part_k<<<dim3(BC, SGS), blk, 0, stream>>>(Z, X, part + r0);
    // 9) fusion: t = relu(p @ fw1 + fb1)        (BC x 2048, K=7168)
    sgemm_t<64><<<dim3(16, BC / 64, 1), blk, 0, stream>>>(
        Z, SGS * H, 0, fw1, 2 * H, 0, Y, 2 * H, 0, fb1, 0, SGS * H, 1);
    //    final[chunk] = t @ fw2 + fb2           (BC x 1024, K=2048)
    sgemm_t<64><<<dim3(8, BC / 64, 1), blk, 0, stream>>>(
        Y, 2 * H, 0, fw2, H, 0, out + r0 * H, H, 0, fb2, 0, 2 * H, 0);
  }

  // 10) reduce losses; write total + spr_losses after `final` in d_out
  loss_red_k<<<dim3(SGS), blk, 0, stream>>>(part, losses);
  finalize_k<<<dim3(1), dim3(64), 0, stream>>>(losses, semw, out + (i64)BATCH * H);
}

// Round 3
// 2889.365 us; speedup vs baseline: 2.7015x; 2.7015x over previous
//
#include <hip/hip_runtime.h>
#include <hip/hip_bf16.h>

// MultiSemanticSPR: B=4096, H=1024, S=7
// Round 2: all GEMMs -> bf16 MFMA (16x16x32), fp32 accumulate. Inline
// fp32->bf16 reg-staging (no weight-copy buffers; workspace identical to the
// proven round-1 layout, ~88.2 MB). A straight-staged, B transposed-staged
// into [128][40]-bf16 LDS (80B row pad = conflict-free ds_read_b128 frags).
// LN / MGS / loss remain fp32.

#define H 1024
#define SGS 7
#define BATCH 4096
#define BC 1024
#define LDT 40   // LDS row stride in ushorts (80 B)

typedef long long i64;
typedef __attribute__((ext_vector_type(8))) short short8;
typedef __attribute__((ext_vector_type(4))) float f32x4;

__device__ __forceinline__ unsigned short f2bf(float f) {
  __hip_bfloat16 h = __float2bfloat16(f);   // RNE hardware convert
  return __builtin_bit_cast(unsigned short, h);
}

__device__ __forceinline__ float block_red(float v, float* scr) {
#pragma unroll
  for (int o = 32; o; o >>= 1) v += __shfl_down(v, o);
  int w = threadIdx.x >> 6;
  if ((threadIdx.x & 63) == 0) scr[w] = v;
  __syncthreads();
  v = scr[0] + scr[1] + scr[2] + scr[3];
  __syncthreads();
  return v;
}

__device__ __forceinline__ void block_red2(float& a, float& b, float* scr) {
#pragma unroll
  for (int o = 32; o; o >>= 1) { a += __shfl_down(a, o); b += __shfl_down(b, o); }
  int w = threadIdx.x >> 6;
  if ((threadIdx.x & 63) == 0) { scr[w] = a; scr[4 + w] = b; }
  __syncthreads();
  a = scr[0] + scr[1] + scr[2] + scr[3];
  b = scr[4] + scr[5] + scr[6] + scr[7];
  __syncthreads();
}

// ---------------- bf16 MFMA GEMM: C = A@B (+bias)(+relu) -------------------
// fp32 in / fp32 out, bf16 MFMA inside. Tile 128x128, BK=32, 4 waves, each
// wave computes 64x64 via 4x4 frags of 16x16. M,N mult of 128, K mult of 32.
__global__ __launch_bounds__(256) void bgemm_k(
    const float* __restrict__ A, int lda, i64 sA,
    const float* __restrict__ Bm, int ldb, i64 sB,
    float* __restrict__ C, int ldc, i64 sC,
    const float* __restrict__ bias, i64 sBias,
    int K, int relu)
{
  A  += (i64)blockIdx.z * sA;
  Bm += (i64)blockIdx.z * sB;
  C  += (i64)blockIdx.z * sC;
  const float* bi = bias ? bias + (i64)blockIdx.z * sBias : nullptr;

  __shared__ __align__(16) unsigned short As[128 * LDT];
  __shared__ __align__(16) unsigned short Bs[128 * LDT];

  const int tid  = threadIdx.x;
  const int lane = tid & 63;
  const int w    = tid >> 6;
  const int wr   = w >> 1, wc = w & 1;   // wave tile: rows wr*64, cols wc*64

  const i64 row0 = (i64)blockIdx.y * 128;
  const i64 col0 = (i64)blockIdx.x * 128;

  // A staging: thread -> row am (2 threads/row), k-halves of 16
  const int am = tid >> 1, akc = (tid & 1) * 16;
  const float* Ap = A + (row0 + am) * (i64)lda + akc;
  // B staging: thread -> 4 k-rows (bk..bk+3) x 4 cols (bn..bn+3)
  const int bk = (tid >> 5) * 4, bn = (tid & 31) * 4;
  const float* Bp = Bm + (i64)bk * ldb + col0 + bn;

  f32x4 acc[4][4];
#pragma unroll
  for (int i = 0; i < 4; ++i)
#pragma unroll
    for (int j = 0; j < 4; ++j) acc[i][j] = (f32x4){0.f, 0.f, 0.f, 0.f};

  for (int k0 = 0; k0 < K; k0 += 32) {
    float4 a0 = *(const float4*)(Ap + k0);
    float4 a1 = *(const float4*)(Ap + k0 + 4);
    float4 a2 = *(const float4*)(Ap + k0 + 8);
    float4 a3 = *(const float4*)(Ap + k0 + 12);
    float4 b0 = *(const float4*)(Bp + (i64)(k0 + 0) * ldb);
    float4 b1 = *(const float4*)(Bp + (i64)(k0 + 1) * ldb);
    float4 b2 = *(const float4*)(Bp + (i64)(k0 + 2) * ldb);
    float4 b3 = *(const float4*)(Bp + (i64)(k0 + 3) * ldb);
    __syncthreads();  // prior iter's frag reads done before overwrite
    {
      ushort4 p;
      p = make_ushort4(f2bf(a0.x), f2bf(a0.y), f2bf(a0.z), f2bf(a0.w));
      *(ushort4*)&As[am * LDT + akc + 0] = p;
      p = make_ushort4(f2bf(a1.x), f2bf(a1.y), f2bf(a1.z), f2bf(a1.w));
      *(ushort4*)&As[am * LDT + akc + 4] = p;
      p = make_ushort4(f2bf(a2.x), f2bf(a2.y), f2bf(a2.z), f2bf(a2.w));
      *(ushort4*)&As[am * LDT + akc + 8] = p;
      p = make_ushort4(f2bf(a3.x), f2bf(a3.y), f2bf(a3.z), f2bf(a3.w));
      *(ushort4*)&As[am * LDT + akc + 12] = p;
      // B transposed: column i of the 4x4 block -> row (bn+i), k bk..bk+3
      p = make_ushort4(f2bf(b0.x), f2bf(b1.x), f2bf(b2.x), f2bf(b3.x));
      *(ushort4*)&Bs[(bn + 0) * LDT + bk] = p;
      p = make_ushort4(f2bf(b0.y), f2bf(b1.y), f2bf(b2.y), f2bf(b3.y));
      *(ushort4*)&Bs[(bn + 1) * LDT + bk] = p;
      p = make_ushort4(f2bf(b0.z), f2bf(b1.z), f2bf(b2.z), f2bf(b3.z));
      *(ushort4*)&Bs[(bn + 2) * LDT + bk] = p;
      p = make_ushort4(f2bf(b0.w), f2bf(b1.w), f2bf(b2.w), f2bf(b3.w));
      *(ushort4*)&Bs[(bn + 3) * LDT + bk] = p;
    }
    __syncthreads();
    short8 af[4], bf[4];
    const int kq = (lane >> 4) * 8, lr = lane & 15;
#pragma unroll
    for (int mf = 0; mf < 4; ++mf)
      af[mf] = *(const short8*)&As[(wr * 64 + mf * 16 + lr) * LDT + kq];
#pragma unroll
    for (int nf = 0; nf < 4; ++nf)
      bf[nf] = *(const short8*)&Bs[(wc * 64 + nf * 16 + lr) * LDT + kq];
#pragma unroll
    for (int mf = 0; mf < 4; ++mf)
#pragma unroll
      for (int nf = 0; nf < 4; ++nf)
        acc[mf][nf] = __builtin_amdgcn_mfma_f32_16x16x32_bf16(
            af[mf], bf[nf], acc[mf][nf], 0, 0, 0);
  }

  // epilogue: D col = lane&15, row = (lane>>4)*4 + reg   [verified layout]
  const int cl = lane & 15, rg = lane >> 4;
#pragma unroll
  for (int nf = 0; nf < 4; ++nf) {
    const i64 col = col0 + wc * 64 + nf * 16 + cl;
    const float bv = bi ? bi[col] : 0.f;
#pragma unroll
    for (int mf = 0; mf < 4; ++mf) {
#pragma unroll
      for (int r = 0; r < 4; ++r) {
        const i64 row = row0 + wr * 64 + mf * 16 + rg * 4 + r;
        float v = acc[mf][nf][r] + bv;
        C[row * (i64)ldc + col] = relu ? fmaxf(v, 0.f) : v;
      }
    }
  }
}

// ---------------- LayerNorm + exact GELU, one row (H=1024) per block --------
__global__ __launch_bounds__(256) void ln_gelu_k(
    const float* __restrict__ x, const float* __restrict__ gamma,
    const float* __restrict__ beta, float* __restrict__ y)
{
  __shared__ float scr[8];
  const i64 row = blockIdx.x;
  const float* xr = x + row * H;
  float* yr = y + row * H;
  const int c = threadIdx.x * 4;
  float4 v = *(const float4*)(xr + c);
  float s = v.x + v.y + v.z + v.w;
  float q = v.x * v.x + v.y * v.y + v.z * v.z + v.w * v.w;
  block_red2(s, q, scr);
  const float mu = s * (1.f / H);
  const float var = q * (1.f / H) - mu * mu;
  const float rstd = rsqrtf(var + 1e-5f);
  float4 g4 = *(const float4*)(gamma + c);
  float4 b4 = *(const float4*)(beta + c);
  float t[4] = {(v.x - mu) * rstd * g4.x + b4.x,
                (v.y - mu) * rstd * g4.y + b4.y,
                (v.z - mu) * rstd * g4.z + b4.z,
                (v.w - mu) * rstd * g4.w + b4.w};
  float o[4];
#pragma unroll
  for (int i = 0; i < 4; ++i)
    o[i] = 0.5f * t[i] * (1.f + erff(t[i] * 0.70710678118654752f));
  *(float4*)(yr + c) = make_float4(o[0], o[1], o[2], o[3]);
}

// ------------- Modified Gram-Schmidt, in-place safe (block-exclusive) ------
__global__ __launch_bounds__(256) void gram_schmidt_k(
    const float* __restrict__ sem, float* __restrict__ h)
{
  __shared__ float V[SGS][H];
  __shared__ float scr[8];
  const i64 b = blockIdx.x;
  const float* src = sem + b * (i64)(SGS * H);
  float* dst = h + b * (i64)(SGS * H);
  for (int e = threadIdx.x; e < SGS * H; e += 256) ((float*)V)[e] = src[e];
  __syncthreads();
  for (int i = 0; i < SGS; ++i) {
    for (int j = 0; j < i; ++j) {
      float dd = 0.f, cc = 0.f;
      for (int e = threadIdx.x; e < H; e += 256) {
        float qv = V[j][e], xv = V[i][e];
        dd += qv * qv; cc += xv * qv;
      }
      block_red2(dd, cc, scr);
      const float proj = (sqrtf(dd) > 1e-6f) ? cc / dd : 0.f;
      for (int e = threadIdx.x; e < H; e += 256) V[i][e] -= proj * V[j][e];
      __syncthreads();
    }
    float nn = 0.f;
    for (int e = threadIdx.x; e < H; e += 256) { float xv = V[i][e]; nn += xv * xv; }
    nn = block_red(nn, scr);
    const float n = sqrtf(nn);
    if (n > 1e-6f) {  // fallback branch statistically unreachable here
      const float inv = 1.f / n;
      for (int e = threadIdx.x; e < H; e += 256) V[i][e] *= inv;
    }
    __syncthreads();
  }
  for (int e = threadIdx.x; e < SGS * H; e += 256) dst[e] = ((float*)V)[e];
}

// --------- loss: sum((p-h)^2) per (b,s) into part[s*BATCH + b_global] ------
__global__ __launch_bounds__(256) void loss_part_k(
    const float* __restrict__ p, const float* __restrict__ h,
    float* __restrict__ part)  // part pre-offset by chunk row0
{
  __shared__ float scr[8];
  const i64 b = blockIdx.x;
  const int s = blockIdx.y;
  const i64 base = b * (i64)(SGS * H) + (i64)s * H;
  const int e = threadIdx.x * 4;
  float4 pv = *(const float4*)(p + base + e);
  float4 hv = *(const float4*)(h + base + e);
  float d0 = pv.x - hv.x, d1 = pv.y - hv.y, d2 = pv.z - hv.z, d3 = pv.w - hv.w;
  float acc = d0 * d0 + d1 * d1 + d2 * d2 + d3 * d3;
  acc = block_red(acc, scr);
  if (threadIdx.x == 0) part[(i64)s * BATCH + b] = acc;
}

__global__ __launch_bounds__(256) void loss_red_k(
    const float* __restrict__ part, float* __restrict__ losses)
{
  __shared__ float scr[8];
  const int s = blockIdx.x;
  float acc = 0.f;
  for (int e = threadIdx.x; e < BATCH; e += 256) acc += part[(i64)s * BATCH + e];
  acc = block_red(acc, scr);
  if (threadIdx.x == 0) losses[s] = acc / (float)((i64)BATCH * H);
}

__global__ void finalize_k(const float* __restrict__ losses,
                           const float* __restrict__ w, float* __restrict__ o)
{
  if (threadIdx.x == 0) {
    float t = 0.f;
#pragma unroll
    for (int s = 0; s < SGS; ++s) { float l = losses[s]; o[1 + s] = l; t += w[s] * l; }
    o[0] = t;
  }
}

// ---------------------------------------------------------------------------
extern "C" void kernel_launch(void* const* d_in, const int* in_sizes, int n_in,
                              void* d_out, int out_size, void* d_ws, size_t ws_size,
                              hipStream_t stream)
{
  (void)in_sizes; (void)n_in; (void)out_size; (void)ws_size;
  const float* sent    = (const float*)d_in[0];
  const float* decompW = (const float*)d_in[1];
  const float* ln_g    = (const float*)d_in[2];
  const float* ln_b    = (const float*)d_in[3];
  const float* pw1     = (const float*)d_in[4];
  const float* pb1     = (const float*)d_in[5];
  const float* pw2     = (const float*)d_in[6];
  const float* pb2     = (const float*)d_in[7];
  const float* qw1     = (const float*)d_in[8];
  const float* qb1     = (const float*)d_in[9];
  const float* qw2     = (const float*)d_in[10];
  const float* qb2     = (const float*)d_in[11];
  const float* fw1     = (const float*)d_in[12];
  const float* fb1     = (const float*)d_in[13];
  const float* fw2     = (const float*)d_in[14];
  const float* fb2     = (const float*)d_in[15];
  const float* semw    = (const float*)d_in[16];
  float* out = (float*)d_out;

  // workspace: 3 chunk slabs + loss partials (~88.2 MB, proven in round 1)
  float* ws = (float*)d_ws;
  const i64 CS = (i64)BC * SGS * H;             // 7,340,032 floats / chunk slab
  float* X      = ws;                           // sem -> h (MGS in place)
  float* Y      = ws + CS;                      // z1 -> p1 -> fusion hidden t
  float* Z      = ws + 2 * CS;                  // z2 -> p
  float* part   = ws + 3 * CS;                  // SGS*BATCH loss partials
  float* losses = part + (i64)SGS * BATCH;      // SGS floats

  const dim3 blk(256);
  const i64 HH = (i64)H * H;

  for (int c = 0; c < BATCH / BC; ++c) {
    const i64 r0 = (i64)c * BC;
    // 1) decomposed = sent[chunk] @ decompW     (BC x 7168, K=1024)
    bgemm_k<<<dim3(56, BC / 128, 1), blk, 0, stream>>>(
        sent + r0 * H, H, 0, decompW, SGS * H, 0, X, SGS * H, 0, nullptr, 0, H, 0);
    // 2) sem = gelu(LN(decomposed)) in place
    ln_gelu_k<<<dim3(BC * SGS), blk, 0, stream>>>(X, ln_g, ln_b, X);
    // 3) h = MGS(sem), in place
    gram_schmidt_k<<<dim3(BC), blk, 0, stream>>>(X, X);
    // 4) z1 = relu(h @ pw1 + pb1)
    bgemm_k<<<dim3(8, BC / 128, SGS), blk, 0, stream>>>(
        X, SGS * H, H, pw1, H, HH, Y, SGS * H, H, pb1, H, H, 1);
    // 5) z2 = z1 @ pw2 + pb2
    bgemm_k<<<dim3(8, BC / 128, SGS), blk, 0, stream>>>(
        Y, SGS * H, H, pw2, H, HH, Z, SGS * H, H, pb2, H, H, 0);
    // 6) p1 = relu(z2 @ qw1 + qb1)
    bgemm_k<<<dim3(8, BC / 128, SGS), blk, 0, stream>>>(
        Z, SGS * H, H, qw1, H, HH, Y, SGS * H, H, qb1, H, H, 1);
    // 7) p = p1 @ qw2 + qb2
    bgemm_k<<<dim3(8, BC / 128, SGS), blk, 0, stream>>>(
        Y, SGS * H, H, qw2, H, HH, Z, SGS * H, H, qb2, H, H, 0);
    // 8) loss partials for this chunk (p fp32 vs h fp32)
    loss_part_k<<<dim3(BC, SGS), blk, 0, stream>>>(Z, X, part + r0);
    // 9) fusion: t = relu(p @ fw1 + fb1)        (BC x 2048, K=7168)
    bgemm_k<<<dim3(16, BC / 128, 1), blk, 0, stream>>>(
        Z, SGS * H, 0, fw1, 2 * H, 0, Y, 2 * H, 0, fb1, 0, SGS * H, 1);
    //    final[chunk] = t @ fw2 + fb2           (BC x 1024, K=2048)
    bgemm_k<<<dim3(8, BC / 128, 1), blk, 0, stream>>>(
        Y, 2 * H, 0, fw2, H, 0, out + r0 * H, H, 0, fb2, 0, 2 * H, 0);
  }

  // 10) reduce losses; write total + spr_losses after `final` in d_out
  loss_red_k<<<dim3(SGS), blk, 0, stream>>>(part, losses);
  finalize_k<<<dim3(1), dim3(64), 0, stream>>>(losses, semw, out + (i64)BATCH * H);
}

// Round 4
// 1737.465 us; speedup vs baseline: 4.4925x; 1.6630x over previous
//
#include <hip/hip_runtime.h>
#include <hip/hip_bf16.h>

// MultiSemanticSPR: B=4096, H=1024, S=7
// Round 3: GEMM rework for latency: 64x128 tile (4 waves, 32x64/wave), BK=64,
// register-prefetch of next K-tile (loads overlap MFMA), slot-XOR LDS swizzle
// (B-transpose writes 16-way -> 4-way). Runtime-adaptive workspace tiers:
//   A (>=~210MB): bf16 P + fp32 T -> full-batch fusion1 (1024 blk) + fusion2
//   M (>=~123MB): fp32 T -> full-batch fusion2
//   B: proven 88.3MB per-chunk layout.

#define H 1024
#define SGS 7
#define BATCH 4096
#define BC 1024
#define LDT 72   // shorts per LDS row (144B = 9x16B: slot-aligned, 36 words)

typedef long long i64;
typedef __attribute__((ext_vector_type(8))) short short8;
typedef __attribute__((ext_vector_type(4))) float f32x4;

__device__ __forceinline__ unsigned short f2bf(float f) {
  __hip_bfloat16 h = __float2bfloat16(f);   // RNE hardware convert
  return __builtin_bit_cast(unsigned short, h);
}

__device__ __forceinline__ short8 pack8(float4 a, float4 b) {
  short8 r;
  r[0] = (short)f2bf(a.x); r[1] = (short)f2bf(a.y);
  r[2] = (short)f2bf(a.z); r[3] = (short)f2bf(a.w);
  r[4] = (short)f2bf(b.x); r[5] = (short)f2bf(b.y);
  r[6] = (short)f2bf(b.z); r[7] = (short)f2bf(b.w);
  return r;
}

// LDS index (in shorts) with slot swizzle: slot' = slot ^ ((row>>2)&7)
__device__ __forceinline__ int lidx(int row, int slot) {
  return row * LDT + ((slot ^ ((row >> 2) & 7)) << 3);
}

__device__ __forceinline__ float block_red(float v, float* scr) {
#pragma unroll
  for (int o = 32; o; o >>= 1) v += __shfl_down(v, o);
  int w = threadIdx.x >> 6;
  if ((threadIdx.x & 63) == 0) scr[w] = v;
  __syncthreads();
  v = scr[0] + scr[1] + scr[2] + scr[3];
  __syncthreads();
  return v;
}

__device__ __forceinline__ void block_red2(float& a, float& b, float* scr) {
#pragma unroll
  for (int o = 32; o; o >>= 1) { a += __shfl_down(a, o); b += __shfl_down(b, o); }
  int w = threadIdx.x >> 6;
  if ((threadIdx.x & 63) == 0) { scr[w] = a; scr[4 + w] = b; }
  __syncthreads();
  a = scr[0] + scr[1] + scr[2] + scr[3];
  b = scr[4] + scr[5] + scr[6] + scr[7];
  __syncthreads();
}

// ---------------- bf16 MFMA GEMM: C = A@B (+bias)(+relu) -------------------
// Tile 64x128, BK=64, 4 waves each 32x64 (2x4 frags of 16x16x32).
// A fp32 (ABF16=0) or bf16 (ABF16=1); B fp32 row-major (transposed-staged);
// C fp32. M mult 64, N mult 128, K mult 64. Grid (N/128, M/64, z).
template <int ABF16>
__global__ __launch_bounds__(256) void bgemm_k(
    const void* __restrict__ Av, int lda, i64 sA,
    const float* __restrict__ Bm, int ldb, i64 sB,
    float* __restrict__ C, int ldc, i64 sC,
    const float* __restrict__ bias, i64 sBias,
    int K, int relu)
{
  __shared__ __align__(16) unsigned short As[64 * LDT];
  __shared__ __align__(16) unsigned short Bs[128 * LDT];

  const int tid  = threadIdx.x;
  const int lane = tid & 63;
  const int w    = tid >> 6;
  const int wr   = w >> 1, wc = w & 1;   // wave tile: rows wr*32, cols wc*64

  const i64 row0 = (i64)blockIdx.y * 64;
  const i64 col0 = (i64)blockIdx.x * 128;

  const float* Af = (const float*)Av + (i64)blockIdx.z * sA;
  const unsigned short* Ab = (const unsigned short*)Av + (i64)blockIdx.z * sA;
  Bm += (i64)blockIdx.z * sB;
  C  += (i64)blockIdx.z * sC;
  const float* bi = bias ? bias + (i64)blockIdx.z * sBias : nullptr;

  // A staging: thread -> row arow, 16 consecutive k at akc
  const int arow = tid >> 2, akc = (tid & 3) * 16;
  // B staging: thread -> 8 k-rows at bkr x 4 cols at bnc (transposed store)
  const int bkr = (tid >> 5) * 8, bnc = (tid & 31) * 4;

  const float* Ap = Af + (row0 + arow) * (i64)lda + akc;
  const unsigned short* Apb = Ab + (row0 + arow) * (i64)lda + akc;
  const float* Bp = Bm + (i64)bkr * ldb + col0 + bnc;

  f32x4 acc[2][4];
#pragma unroll
  for (int i = 0; i < 2; ++i)
#pragma unroll
    for (int j = 0; j < 4; ++j) acc[i][j] = (f32x4){0.f, 0.f, 0.f, 0.f};

  float4 ra[4]; short8 ua[2]; float4 rb[8];

  // prologue: load k-tile 0
  if constexpr (ABF16) {
    ua[0] = *(const short8*)(const void*)(Apb + 0);
    ua[1] = *(const short8*)(const void*)(Apb + 8);
  } else {
#pragma unroll
    for (int i = 0; i < 4; ++i) ra[i] = *(const float4*)(Ap + i * 4);
  }
#pragma unroll
  for (int j = 0; j < 8; ++j) rb[j] = *(const float4*)(Bp + (i64)j * ldb);

  const int kSteps = K >> 6;
  for (int s = 0; s < kSteps; ++s) {
    __syncthreads();  // prior frag reads done before overwrite
    // stage current tile into LDS (bf16)
    {
      short8 a0, a1;
      if constexpr (ABF16) { a0 = ua[0]; a1 = ua[1]; }
      else { a0 = pack8(ra[0], ra[1]); a1 = pack8(ra[2], ra[3]); }
      const int sa = (tid & 3) * 2;
      *(short8*)(void*)&As[lidx(arow, sa)]     = a0;
      *(short8*)(void*)&As[lidx(arow, sa + 1)] = a1;
      const int sb = tid >> 5;
#pragma unroll
      for (int i = 0; i < 4; ++i) {
        short8 p;
#pragma unroll
        for (int j = 0; j < 8; ++j)
          p[j] = (short)f2bf(((const float*)&rb[j])[i]);
        *(short8*)(void*)&Bs[lidx(bnc + i, sb)] = p;
      }
    }
    // prefetch next k-tile into registers (overlaps barrier + MFMA below)
    if (s + 1 < kSteps) {
      const i64 k0 = (i64)(s + 1) * 64;
      if constexpr (ABF16) {
        ua[0] = *(const short8*)(const void*)(Apb + k0);
        ua[1] = *(const short8*)(const void*)(Apb + k0 + 8);
      } else {
#pragma unroll
        for (int i = 0; i < 4; ++i) ra[i] = *(const float4*)(Ap + k0 + i * 4);
      }
#pragma unroll
      for (int j = 0; j < 8; ++j)
        rb[j] = *(const float4*)(Bp + (k0 + j) * (i64)ldb);
    }
    __syncthreads();
    // frags + MFMA (two k-halves of 32)
#pragma unroll
    for (int kh = 0; kh < 2; ++kh) {
      const int ks = kh * 4 + (lane >> 4);
      const int lr = lane & 15;
      short8 af[2], bf[4];
#pragma unroll
      for (int mf = 0; mf < 2; ++mf)
        af[mf] = *(const short8*)(const void*)&As[lidx(wr * 32 + mf * 16 + lr, ks)];
#pragma unroll
      for (int nf = 0; nf < 4; ++nf)
        bf[nf] = *(const short8*)(const void*)&Bs[lidx(wc * 64 + nf * 16 + lr, ks)];
#pragma unroll
      for (int mf = 0; mf < 2; ++mf)
#pragma unroll
        for (int nf = 0; nf < 4; ++nf)
          acc[mf][nf] = __builtin_amdgcn_mfma_f32_16x16x32_bf16(
              af[mf], bf[nf], acc[mf][nf], 0, 0, 0);
    }
  }

  // epilogue: D col = lane&15, row = (lane>>4)*4 + reg  [verified r2]
  const int cl = lane & 15, rg = lane >> 4;
#pragma unroll
  for (int nf = 0; nf < 4; ++nf) {
    const i64 col = col0 + wc * 64 + nf * 16 + cl;
    const float bv = bi ? bi[col] : 0.f;
#pragma unroll
    for (int mf = 0; mf < 2; ++mf) {
#pragma unroll
      for (int r = 0; r < 4; ++r) {
        const i64 row = row0 + wr * 32 + mf * 16 + rg * 4 + r;
        float v = acc[mf][nf][r] + bv;
        C[row * (i64)ldc + col] = relu ? fmaxf(v, 0.f) : v;
      }
    }
  }
}

// ---------------- fp32 -> bf16 convert (8 elems/thread) --------------------
__global__ __launch_bounds__(256) void f2b_k(
    const float* __restrict__ x, unsigned short* __restrict__ y, i64 n)
{
  const i64 i = ((i64)blockIdx.x * 256 + threadIdx.x) * 8;
  if (i + 8 <= n) {
    float4 a = *(const float4*)(x + i);
    float4 b = *(const float4*)(x + i + 4);
    short8 o = pack8(a, b);
    *(short8*)(void*)(y + i) = o;
  }
}

// ---------------- LayerNorm + exact GELU, one row (H=1024) per block --------
__global__ __launch_bounds__(256) void ln_gelu_k(
    const float* __restrict__ x, const float* __restrict__ gamma,
    const float* __restrict__ beta, float* __restrict__ y)
{
  __shared__ float scr[8];
  const i64 row = blockIdx.x;
  const float* xr = x + row * H;
  float* yr = y + row * H;
  const int c = threadIdx.x * 4;
  float4 v = *(const float4*)(xr + c);
  float s = v.x + v.y + v.z + v.w;
  float q = v.x * v.x + v.y * v.y + v.z * v.z + v.w * v.w;
  block_red2(s, q, scr);
  const float mu = s * (1.f / H);
  const float var = q * (1.f / H) - mu * mu;
  const float rstd = rsqrtf(var + 1e-5f);
  float4 g4 = *(const float4*)(gamma + c);
  float4 b4 = *(const float4*)(beta + c);
  float t[4] = {(v.x - mu) * rstd * g4.x + b4.x,
                (v.y - mu) * rstd * g4.y + b4.y,
                (v.z - mu) * rstd * g4.z + b4.z,
                (v.w - mu) * rstd * g4.w + b4.w};
  float o[4];
#pragma unroll
  for (int i = 0; i < 4; ++i)
    o[i] = 0.5f * t[i] * (1.f + erff(t[i] * 0.70710678118654752f));
  *(float4*)(yr + c) = make_float4(o[0], o[1], o[2], o[3]);
}

// ------------- Modified Gram-Schmidt, in-place safe (block-exclusive) ------
__global__ __launch_bounds__(256) void gram_schmidt_k(
    const float* __restrict__ sem, float* __restrict__ h)
{
  __shared__ float V[SGS][H];
  __shared__ float scr[8];
  const i64 b = blockIdx.x;
  const float* src = sem + b * (i64)(SGS * H);
  float* dst = h + b * (i64)(SGS * H);
  for (int e = threadIdx.x; e < SGS * H; e += 256) ((float*)V)[e] = src[e];
  __syncthreads();
  for (int i = 0; i < SGS; ++i) {
    for (int j = 0; j < i; ++j) {
      float dd = 0.f, cc = 0.f;
      for (int e = threadIdx.x; e < H; e += 256) {
        float qv = V[j][e], xv = V[i][e];
        dd += qv * qv; cc += xv * qv;
      }
      block_red2(dd, cc, scr);
      const float proj = (sqrtf(dd) > 1e-6f) ? cc / dd : 0.f;
      for (int e = threadIdx.x; e < H; e += 256) V[i][e] -= proj * V[j][e];
      __syncthreads();
    }
    float nn = 0.f;
    for (int e = threadIdx.x; e < H; e += 256) { float xv = V[i][e]; nn += xv * xv; }
    nn = block_red(nn, scr);
    const float n = sqrtf(nn);
    if (n > 1e-6f) {  // fallback branch statistically unreachable here
      const float inv = 1.f / n;
      for (int e = threadIdx.x; e < H; e += 256) V[i][e] *= inv;
    }
    __syncthreads();
  }
  for (int e = threadIdx.x; e < SGS * H; e += 256) dst[e] = ((float*)V)[e];
}

// --------- loss: sum((p-h)^2) per (b,s) into part[s*BATCH + b_global] ------
__global__ __launch_bounds__(256) void loss_part_k(
    const float* __restrict__ p, const float* __restrict__ h,
    float* __restrict__ part)  // part pre-offset by chunk row0
{
  __shared__ float scr[8];
  const i64 b = blockIdx.x;
  const int s = blockIdx.y;
  const i64 base = b * (i64)(SGS * H) + (i64)s * H;
  const int e = threadIdx.x * 4;
  float4 pv = *(const float4*)(p + base + e);
  float4 hv = *(const float4*)(h + base + e);
  float d0 = pv.x - hv.x, d1 = pv.y - hv.y, d2 = pv.z - hv.z, d3 = pv.w - hv.w;
  float acc = d0 * d0 + d1 * d1 + d2 * d2 + d3 * d3;
  acc = block_red(acc, scr);
  if (threadIdx.x == 0) part[(i64)s * BATCH + b] = acc;
}

__global__ __launch_bounds__(256) void loss_red_k(
    const float* __restrict__ part, float* __restrict__ losses)
{
  __shared__ float scr[8];
  const int s = blockIdx.x;
  float acc = 0.f;
  for (int e = threadIdx.x; e < BATCH; e += 256) acc += part[(i64)s * BATCH + e];
  acc = block_red(acc, scr);
  if (threadIdx.x == 0) losses[s] = acc / (float)((i64)BATCH * H);
}

__global__ void finalize_k(const float* __restrict__ losses,
                           const float* __restrict__ w, float* __restrict__ o)
{
  if (threadIdx.x == 0) {
    float t = 0.f;
#pragma unroll
    for (int s = 0; s < SGS; ++s) { float l = losses[s]; o[1 + s] = l; t += w[s] * l; }
    o[0] = t;
  }
}

// ---------------------------------------------------------------------------
extern "C" void kernel_launch(void* const* d_in, const int* in_sizes, int n_in,
                              void* d_out, int out_size, void* d_ws, size_t ws_size,
                              hipStream_t stream)
{
  (void)in_sizes; (void)n_in; (void)out_size;
  const float* sent    = (const float*)d_in[0];
  const float* decompW = (const float*)d_in[1];
  const float* ln_g    = (const float*)d_in[2];
  const float* ln_b    = (const float*)d_in[3];
  const float* pw1     = (const float*)d_in[4];
  const float* pb1     = (const float*)d_in[5];
  const float* pw2     = (const float*)d_in[6];
  const float* pb2     = (const float*)d_in[7];
  const float* qw1     = (const float*)d_in[8];
  const float* qb1     = (const float*)d_in[9];
  const float* qw2     = (const float*)d_in[10];
  const float* qb2     = (const float*)d_in[11];
  const float* fw1     = (const float*)d_in[12];
  const float* fb1     = (const float*)d_in[13];
  const float* fw2     = (const float*)d_in[14];
  const float* fb2     = (const float*)d_in[15];
  const float* semw    = (const float*)d_in[16];
  float* out = (float*)d_out;

  float* ws = (float*)d_ws;
  const i64 CS = (i64)BC * SGS * H;             // 7,340,032 floats / chunk slab
  float* X      = ws;                           // sem -> h (MGS in place)
  float* Y      = ws + CS;                      // z1 -> p1 (-> t in tier B)
  float* Z      = ws + 2 * CS;                  // z2 -> p
  float* part   = ws + 3 * CS;                  // SGS*BATCH loss partials
  float* losses = part + (i64)SGS * BATCH;      // SGS floats
  float* endB   = losses + 16;

  const i64 baseFl = (i64)(endB - ws);          // 22,048,784 floats (88.2 MB)
  const i64 Tfl    = (i64)BATCH * 2 * H;        // 8,388,608 floats (33.5 MB)
  const i64 Pfl    = (i64)BATCH * SGS * H / 2;  // bf16 P in float units (58.7MB)
  const bool tierM = ws_size >= (size_t)(baseFl + Tfl) * 4;
  const bool tierA = ws_size >= (size_t)(baseFl + Tfl + Pfl) * 4;
  float* T = endB;                              // fp32 fusion hidden (4096x2048)
  unsigned short* P = (unsigned short*)(endB + Tfl);  // bf16 p (4096x7168)

  const dim3 blk(256);
  const i64 HH = (i64)H * H;

  for (int c = 0; c < BATCH / BC; ++c) {
    const i64 r0 = (i64)c * BC;
    // 1) decomposed = sent[chunk] @ decompW     (BC x 7168, K=1024)
    bgemm_k<0><<<dim3(56, BC / 64, 1), blk, 0, stream>>>(
        sent + r0 * H, H, 0, decompW, SGS * H, 0, X, SGS * H, 0, nullptr, 0, H, 0);
    // 2) sem = gelu(LN(decomposed)) in place
    ln_gelu_k<<<dim3(BC * SGS), blk, 0, stream>>>(X, ln_g, ln_b, X);
    // 3) h = MGS(sem), in place
    gram_schmidt_k<<<dim3(BC), blk, 0, stream>>>(X, X);
    // 4-7) per-semantic SPR heads
    bgemm_k<0><<<dim3(8, BC / 64, SGS), blk, 0, stream>>>(
        X, SGS * H, H, pw1, H, HH, Y, SGS * H, H, pb1, H, H, 1);
    bgemm_k<0><<<dim3(8, BC / 64, SGS), blk, 0, stream>>>(
        Y, SGS * H, H, pw2, H, HH, Z, SGS * H, H, pb2, H, H, 0);
    bgemm_k<0><<<dim3(8, BC / 64, SGS), blk, 0, stream>>>(
        Z, SGS * H, H, qw1, H, HH, Y, SGS * H, H, qb1, H, H, 1);
    bgemm_k<0><<<dim3(8, BC / 64, SGS), blk, 0, stream>>>(
        Y, SGS * H, H, qw2, H, HH, Z, SGS * H, H, qb2, H, H, 0);
    // 8) loss partials for this chunk
    loss_part_k<<<dim3(BC, SGS), blk, 0, stream>>>(Z, X, part + r0);
    // 9) fusion path, tiered
    if (tierA) {
      // stash p as bf16 for the full-batch fusion1 later
      f2b_k<<<dim3((unsigned)(CS / 2048)), blk, 0, stream>>>(
          Z, P + r0 * (SGS * H), CS);
    } else if (tierM) {
      // per-chunk fusion1 into persistent T
      bgemm_k<0><<<dim3(16, BC / 64, 1), blk, 0, stream>>>(
          Z, SGS * H, 0, fw1, 2 * H, 0, T + r0 * 2 * H, 2 * H, 0, fb1, 0, SGS * H, 1);
    } else {
      bgemm_k<0><<<dim3(16, BC / 64, 1), blk, 0, stream>>>(
          Z, SGS * H, 0, fw1, 2 * H, 0, Y, 2 * H, 0, fb1, 0, SGS * H, 1);
      bgemm_k<0><<<dim3(8, BC / 64, 1), blk, 0, stream>>>(
          Y, 2 * H, 0, fw2, H, 0, out + r0 * H, H, 0, fb2, 0, 2 * H, 0);
    }
  }

  if (tierA) {
    // fusion1 full-batch, bf16 A: (4096 x 2048, K=7168) -> T
    bgemm_k<1><<<dim3(16, BATCH / 64, 1), blk, 0, stream>>>(
        P, SGS * H, 0, fw1, 2 * H, 0, T, 2 * H, 0, fb1, 0, SGS * H, 1);
  }
  if (tierA || tierM) {
    // fusion2 full-batch: (4096 x 1024, K=2048) -> out
    bgemm_k<0><<<dim3(8, BATCH / 64, 1), blk, 0, stream>>>(
        T, 2 * H, 0, fw2, H, 0, out, H, 0, fb2, 0, 2 * H, 0);
  }

  // 10) reduce losses; write total + spr_losses after `final` in d_out
  loss_red_k<<<dim3(SGS), blk, 0, stream>>>(part, losses);
  finalize_k<<<dim3(1), dim3(64), 0, stream>>>(losses, semw, out + (i64)BATCH * H);
}

// Round 5
// 1513.802 us; speedup vs baseline: 5.1562x; 1.1477x over previous
//
#include <hip/hip_runtime.h>
#include <hip/hip_bf16.h>

// MultiSemanticSPR: B=4096, H=1024, S=7
// Round 4: (1) GEMM: 512-thread 128x128 tile, BK=32, double-buffered LDS,
// ONE barrier/K-step, reg-prefetch; (2) bf16 intermediates (epilogue writes
// bf16 directly; p dual fp32+bf16); (3) LN+GELU+MGS fused, one wave per row,
// all-register, shfl-only reductions. Workspace 178.4MB (<=180.4 proven).

#define H 1024
#define SGS 7
#define BATCH 4096
#define BC 1024
#define EPS 1e-6f

typedef long long i64;
typedef __attribute__((ext_vector_type(8))) short short8;
typedef __attribute__((ext_vector_type(4))) float f32x4;

__device__ __forceinline__ unsigned short f2bf(float f) {
  __hip_bfloat16 h = __float2bfloat16(f);   // RNE
  return __builtin_bit_cast(unsigned short, h);
}
__device__ __forceinline__ float b2f(unsigned short u) {
  unsigned int x = ((unsigned int)u) << 16;
  return __builtin_bit_cast(float, x);
}
__device__ __forceinline__ short8 pack8(float4 a, float4 b) {
  short8 r;
  r[0] = (short)f2bf(a.x); r[1] = (short)f2bf(a.y);
  r[2] = (short)f2bf(a.z); r[3] = (short)f2bf(a.w);
  r[4] = (short)f2bf(b.x); r[5] = (short)f2bf(b.y);
  r[6] = (short)f2bf(b.z); r[7] = (short)f2bf(b.w);
  return r;
}

// LDS index (shorts), rows of 32 shorts padded to 40; 16B slots 0..3 XOR-swz
__device__ __forceinline__ int lidx(int row, int slot) {
  return row * 40 + ((slot ^ ((row >> 2) & 3)) << 3);
}

// ---------------- bf16 MFMA GEMM ------------------------------------------
// C = A@B (+bias)(+relu). A fp32 or bf16 (ABF16), B fp32 row-major
// (transpose-staged). OM bit0: write fp32 Cf, bit1: write bf16 Cb.
// Tile 128x128, BK=32, 512 thr (8 waves, 32x64 each). Grid (N/128, M/128, z).
template <int ABF16, int OM>
__global__ __launch_bounds__(512) void bgemm_k(
    const void* __restrict__ Av, int lda, i64 sA,
    const float* __restrict__ Bm, int ldb, i64 sB,
    float* __restrict__ Cf, unsigned short* __restrict__ Cb, int ldc, i64 sC,
    const float* __restrict__ bias, i64 sBias, int K, int relu)
{
  __shared__ __align__(16) unsigned short As[2][128 * 40];
  __shared__ __align__(16) unsigned short Bs[2][128 * 40];

  const int tid  = threadIdx.x;
  const int lane = tid & 63;
  const int w    = tid >> 6;
  const int wr   = w >> 1, wc = w & 1;   // wave tile rows wr*32, cols wc*64

  const i64 row0 = (i64)blockIdx.y * 128;
  const i64 col0 = (i64)blockIdx.x * 128;

  const float* Af = (const float*)Av + (i64)blockIdx.z * sA;
  const unsigned short* Ab = (const unsigned short*)Av + (i64)blockIdx.z * sA;
  Bm += (i64)blockIdx.z * sB;
  if (OM & 1) Cf += (i64)blockIdx.z * sC;
  if (OM & 2) Cb += (i64)blockIdx.z * sC;
  const float* bi = bias ? bias + (i64)blockIdx.z * sBias : nullptr;

  // A staging: thread -> row arow (0..127), 8 k at akc
  const int arow = tid >> 2, akc = (tid & 3) * 8;
  const float* Ap = Af + (row0 + arow) * (i64)lda + akc;
  const unsigned short* Apb = Ab + (row0 + arow) * (i64)lda + akc;
  // B staging: thread -> 2 k-rows at bk x 4 cols at bcol (transposed store)
  const int bcol = (tid & 31) * 4, bk = (tid >> 5) * 2;
  const float* Bp = Bm + (i64)bk * ldb + col0 + bcol;

  f32x4 acc[2][4];
#pragma unroll
  for (int i = 0; i < 2; ++i)
#pragma unroll
    for (int j = 0; j < 4; ++j) acc[i][j] = (f32x4){0.f, 0.f, 0.f, 0.f};

  float4 ra0, ra1; short8 ua; float4 rb0, rb1;

  // prologue: load k-tile 0
  if constexpr (ABF16) ua = *(const short8*)(const void*)(Apb);
  else { ra0 = *(const float4*)(Ap); ra1 = *(const float4*)(Ap + 4); }
  rb0 = *(const float4*)(Bp);
  rb1 = *(const float4*)(Bp + ldb);

  const int kSteps = K >> 5;
  int buf = 0;
  for (int s = 0; s < kSteps; ++s) {
    // stage current regs -> LDS[buf] (prev iter's barrier legalizes this)
    {
      short8 a8;
      if constexpr (ABF16) a8 = ua; else a8 = pack8(ra0, ra1);
      *(short8*)(void*)&As[buf][lidx(arow, akc >> 3)] = a8;
      const int slot = bk >> 3, kin = bk & 7;
#pragma unroll
      for (int i = 0; i < 4; ++i) {
        const int row = bcol + i;
        ushort2 p2 = make_ushort2(f2bf(((const float*)&rb0)[i]),
                                  f2bf(((const float*)&rb1)[i]));
        *(ushort2*)(void*)&Bs[buf][row * 40 + ((slot ^ ((row >> 2) & 3)) << 3) + kin] = p2;
      }
    }
    // prefetch next k-tile into regs (overlaps barrier + MFMA)
    if (s + 1 < kSteps) {
      const i64 k0 = (i64)(s + 1) * 32;
      if constexpr (ABF16) ua = *(const short8*)(const void*)(Apb + k0);
      else { ra0 = *(const float4*)(Ap + k0); ra1 = *(const float4*)(Ap + k0 + 4); }
      rb0 = *(const float4*)(Bp + k0 * (i64)ldb);
      rb1 = *(const float4*)(Bp + (k0 + 1) * (i64)ldb);
    }
    __syncthreads();
    // frag reads + 8 MFMA from LDS[buf]
    const int kq = lane >> 4, lr = lane & 15;
    short8 af[2], bf[4];
#pragma unroll
    for (int mf = 0; mf < 2; ++mf)
      af[mf] = *(const short8*)(const void*)&As[buf][lidx(wr * 32 + mf * 16 + lr, kq)];
#pragma unroll
    for (int nf = 0; nf < 4; ++nf)
      bf[nf] = *(const short8*)(const void*)&Bs[buf][lidx(wc * 64 + nf * 16 + lr, kq)];
#pragma unroll
    for (int mf = 0; mf < 2; ++mf)
#pragma unroll
      for (int nf = 0; nf < 4; ++nf)
        acc[mf][nf] = __builtin_amdgcn_mfma_f32_16x16x32_bf16(
            af[mf], bf[nf], acc[mf][nf], 0, 0, 0);
    buf ^= 1;
  }

  // epilogue: D col = lane&15, row = (lane>>4)*4 + reg  [verified r2/r3]
  const int cl = lane & 15, rg = lane >> 4;
#pragma unroll
  for (int nf = 0; nf < 4; ++nf) {
    const i64 col = col0 + wc * 64 + nf * 16 + cl;
    const float bv = bi ? bi[col] : 0.f;
#pragma unroll
    for (int mf = 0; mf < 2; ++mf) {
#pragma unroll
      for (int r = 0; r < 4; ++r) {
        const i64 row = row0 + wr * 32 + mf * 16 + rg * 4 + r;
        float v = acc[mf][nf][r] + bv;
        if (relu) v = fmaxf(v, 0.f);
        if (OM & 1) Cf[row * (i64)ldc + col] = v;
        if (OM & 2) Cb[row * (i64)ldc + col] = f2bf(v);
      }
    }
  }
}

// ---------- fused LayerNorm + exact GELU + MGS: one WAVE per batch row -----
// block = 256 (4 waves = 4 rows). All state in registers; shfl-only reduces.
__global__ __launch_bounds__(256) void lnmgs_k(
    const float* __restrict__ X, const float* __restrict__ gamma,
    const float* __restrict__ beta, unsigned short* __restrict__ Hb)
{
  const int wv = threadIdx.x >> 6, l = threadIdx.x & 63;
  const i64 b = (i64)blockIdx.x * 4 + wv;
  const float* xr = X + b * (i64)(SGS * H);

  float g[16], be[16];
#pragma unroll
  for (int q = 0; q < 4; ++q) {
    float4 gv = *(const float4*)(gamma + l * 16 + q * 4);
    float4 bv = *(const float4*)(beta + l * 16 + q * 4);
    g[q*4+0] = gv.x; g[q*4+1] = gv.y; g[q*4+2] = gv.z; g[q*4+3] = gv.w;
    be[q*4+0] = bv.x; be[q*4+1] = bv.y; be[q*4+2] = bv.z; be[q*4+3] = bv.w;
  }

  float V[SGS][16];
#pragma unroll
  for (int s = 0; s < SGS; ++s) {
#pragma unroll
    for (int q = 0; q < 4; ++q) {
      float4 v = *(const float4*)(xr + (i64)s * H + l * 16 + q * 4);
      V[s][q*4+0] = v.x; V[s][q*4+1] = v.y; V[s][q*4+2] = v.z; V[s][q*4+3] = v.w;
    }
    float s1 = 0.f, s2 = 0.f;
#pragma unroll
    for (int e = 0; e < 16; ++e) { s1 += V[s][e]; s2 += V[s][e] * V[s][e]; }
#pragma unroll
    for (int o = 1; o < 64; o <<= 1) { s1 += __shfl_xor(s1, o); s2 += __shfl_xor(s2, o); }
    const float mu = s1 * (1.f / H);
    const float var = s2 * (1.f / H) - mu * mu;
    const float rstd = rsqrtf(var + 1e-5f);
#pragma unroll
    for (int e = 0; e < 16; ++e) {
      float t = (V[s][e] - mu) * rstd * g[e] + be[e];
      V[s][e] = 0.5f * t * (1.f + erff(t * 0.70710678118654752f));
    }
  }

  // modified Gram-Schmidt over the 7 rows (all-register, shfl reduces)
#pragma unroll
  for (int i = 0; i < SGS; ++i) {
#pragma unroll
    for (int j = 0; j < SGS; ++j) {
      if (j < i) {
        float cc = 0.f, dd = 0.f;
#pragma unroll
        for (int e = 0; e < 16; ++e) { cc += V[i][e] * V[j][e]; dd += V[j][e] * V[j][e]; }
#pragma unroll
        for (int o = 1; o < 64; o <<= 1) { cc += __shfl_xor(cc, o); dd += __shfl_xor(dd, o); }
        const float proj = (sqrtf(dd) > EPS) ? cc / dd : 0.f;
#pragma unroll
        for (int e = 0; e < 16; ++e) V[i][e] -= proj * V[j][e];
      }
    }
    float nn = 0.f;
#pragma unroll
    for (int e = 0; e < 16; ++e) nn += V[i][e] * V[i][e];
#pragma unroll
    for (int o = 1; o < 64; o <<= 1) nn += __shfl_xor(nn, o);
    const float n = sqrtf(nn);
    if (n > EPS) {   // fallback branch statistically unreachable here
      const float inv = 1.f / n;
#pragma unroll
      for (int e = 0; e < 16; ++e) V[i][e] *= inv;
    }
  }

  unsigned short* hr = Hb + b * (i64)(SGS * H) + l * 16;
#pragma unroll
  for (int s = 0; s < SGS; ++s) {
    short8 o;
#pragma unroll
    for (int e = 0; e < 8; ++e) o[e] = (short)f2bf(V[s][e]);
    *(short8*)(void*)(hr + (i64)s * H) = o;
#pragma unroll
    for (int e = 0; e < 8; ++e) o[e] = (short)f2bf(V[s][8 + e]);
    *(short8*)(void*)(hr + (i64)s * H + 8) = o;
  }
}

__device__ __forceinline__ float block_red(float v, float* scr) {
#pragma unroll
  for (int o = 32; o; o >>= 1) v += __shfl_down(v, o);
  int w = threadIdx.x >> 6;
  if ((threadIdx.x & 63) == 0) scr[w] = v;
  __syncthreads();
  v = scr[0] + scr[1] + scr[2] + scr[3];
  __syncthreads();
  return v;
}

// --------- loss: sum((p-h)^2), p fp32, h bf16 ------------------------------
__global__ __launch_bounds__(256) void loss_part_k(
    const float* __restrict__ p, const unsigned short* __restrict__ hb,
    float* __restrict__ part)  // part pre-offset by chunk row0
{
  __shared__ float scr[8];
  const i64 b = blockIdx.x;
  const int s = blockIdx.y;
  const i64 base = b * (i64)(SGS * H) + (i64)s * H;
  const int e = threadIdx.x * 4;
  float4 pv = *(const float4*)(p + base + e);
  ushort4 hv = *(const ushort4*)(hb + base + e);
  float d0 = pv.x - b2f(hv.x), d1 = pv.y - b2f(hv.y);
  float d2 = pv.z - b2f(hv.z), d3 = pv.w - b2f(hv.w);
  float acc = d0 * d0 + d1 * d1 + d2 * d2 + d3 * d3;
  acc = block_red(acc, scr);
  if (threadIdx.x == 0) part[(i64)s * BATCH + b] = acc;
}

__global__ __launch_bounds__(256) void loss_red_k(
    const float* __restrict__ part, float* __restrict__ losses)
{
  __shared__ float scr[8];
  const int s = blockIdx.x;
  float acc = 0.f;
  for (int e = threadIdx.x; e < BATCH; e += 256) acc += part[(i64)s * BATCH + e];
  acc = block_red(acc, scr);
  if (threadIdx.x == 0) losses[s] = acc / (float)((i64)BATCH * H);
}

__global__ void finalize_k(const float* __restrict__ losses,
                           const float* __restrict__ w, float* __restrict__ o)
{
  if (threadIdx.x == 0) {
    float t = 0.f;
#pragma unroll
    for (int s = 0; s < SGS; ++s) { float l = losses[s]; o[1 + s] = l; t += w[s] * l; }
    o[0] = t;
  }
}

// ---------------------------------------------------------------------------
extern "C" void kernel_launch(void* const* d_in, const int* in_sizes, int n_in,
                              void* d_out, int out_size, void* d_ws, size_t ws_size,
                              hipStream_t stream)
{
  (void)in_sizes; (void)n_in; (void)out_size; (void)ws_size;
  const float* sent    = (const float*)d_in[0];
  const float* decompW = (const float*)d_in[1];
  const float* ln_g    = (const float*)d_in[2];
  const float* ln_b    = (const float*)d_in[3];
  const float* pw1     = (const float*)d_in[4];
  const float* pb1     = (const float*)d_in[5];
  const float* pw2     = (const float*)d_in[6];
  const float* pb2     = (const float*)d_in[7];
  const float* qw1     = (const float*)d_in[8];
  const float* qb1     = (const float*)d_in[9];
  const float* qw2     = (const float*)d_in[10];
  const float* qb2     = (const float*)d_in[11];
  const float* fw1     = (const float*)d_in[12];
  const float* fb1     = (const float*)d_in[13];
  const float* fw2     = (const float*)d_in[14];
  const float* fb2     = (const float*)d_in[15];
  const float* semw    = (const float*)d_in[16];
  float* out = (float*)d_out;

  // workspace layout (floats), total ~178.4 MB (<= 180.4 proven in r3)
  float* ws = (float*)d_ws;
  const i64 CSf = (i64)BC * SGS * H;              // 7,340,032
  float*          X    = ws;                       // chunk decomposed (fp32)
  float*          Pf   = ws + CSf;                 // chunk p (fp32, loss)
  unsigned short* Hb   = (unsigned short*)(ws + 2 * CSf);          // chunk h bf16
  unsigned short* Yb   = Hb + CSf;                 // chunk z1/p1 bf16
  unsigned short* Zb   = Yb + CSf;                 // chunk z2 bf16
  unsigned short* Pb   = Zb + CSf;                 // FULL p bf16 (4096x7168)
  unsigned short* T    = Pb + (i64)BATCH * SGS * H;// FULL t bf16 (4096x2048)
  float*          part = (float*)(T + (i64)BATCH * 2 * H);  // SGS*BATCH
  float*          losses = part + (i64)SGS * BATCH;

  const dim3 g512(512);
  const dim3 blk(256);
  const i64 HH = (i64)H * H;

  for (int c = 0; c < BATCH / BC; ++c) {
    const i64 r0 = (i64)c * BC;
    // 1) decomposed = sent[chunk] @ decompW  (fp32 out for LN precision)
    bgemm_k<0, 1><<<dim3(56, BC / 128, 1), g512, 0, stream>>>(
        sent + r0 * H, H, 0, decompW, SGS * H, 0, X, nullptr, SGS * H, 0,
        nullptr, 0, H, 0);
    // 2+3) h = MGS(gelu(LN(decomposed))) -> bf16, one wave per row
    lnmgs_k<<<dim3(BC / 4), blk, 0, stream>>>(X, ln_g, ln_b, Hb);
    // 4-7) per-semantic SPR heads (bf16 A, bf16 out)
    bgemm_k<1, 2><<<dim3(8, BC / 128, SGS), g512, 0, stream>>>(
        Hb, SGS * H, H, pw1, H, HH, nullptr, Yb, SGS * H, H, pb1, H, H, 1);
    bgemm_k<1, 2><<<dim3(8, BC / 128, SGS), g512, 0, stream>>>(
        Yb, SGS * H, H, pw2, H, HH, nullptr, Zb, SGS * H, H, pb2, H, H, 0);
    bgemm_k<1, 2><<<dim3(8, BC / 128, SGS), g512, 0, stream>>>(
        Zb, SGS * H, H, qw1, H, HH, nullptr, Yb, SGS * H, H, qb1, H, H, 1);
    //    p: dual write fp32 (loss) + bf16 (fusion A)
    bgemm_k<1, 3><<<dim3(8, BC / 128, SGS), g512, 0, stream>>>(
        Yb, SGS * H, H, qw2, H, HH, Pf, Pb + r0 * SGS * H, SGS * H, H,
        qb2, H, H, 0);
    // 8) loss partials
    loss_part_k<<<dim3(BC, SGS), blk, 0, stream>>>(Pf, Hb, part + r0);
  }

  // 9) fusion full-batch: t = relu(p @ fw1 + fb1); final = t @ fw2 + fb2
  bgemm_k<1, 2><<<dim3(16, BATCH / 128, 1), g512, 0, stream>>>(
      Pb, SGS * H, 0, fw1, 2 * H, 0, nullptr, T, 2 * H, 0, fb1, 0, SGS * H, 1);
  bgemm_k<1, 1><<<dim3(8, BATCH / 128, 1), g512, 0, stream>>>(
      T, 2 * H, 0, fw2, H, 0, out, nullptr, H, 0, fb2, 0, 2 * H, 0);

  // 10) reduce losses; write total + spr_losses after `final` in d_out
  loss_red_k<<<dim3(SGS), blk, 0, stream>>>(part, losses);
  finalize_k<<<dim3(1), dim3(64), 0, stream>>>(losses, semw, out + (i64)BATCH * H);
}